// Round 5
// baseline (760.933 us; speedup 1.0000x reference)
//
#include <hip/hip_runtime.h>
#include <hip/hip_bf16.h>

// NonLocalBlockND + positional encoding, MI355X (gfx950). All-MFMA pipeline.
// R4 -> R5: attn restructured for occupancy + single barrier/tile.
//   Block = 256 thr (4 waves), 32 q-rows, KVBLK=32, m-split x4 (1180 blocks).
//   QK swapped (mfma(K,Q)): D col=l15=q-row -> softmax needs only 2 shfl.
//   Self-contained QK waves: P = exp(S - local_max) + (m,l) to LDS; PV side
//   rescales B-frags by exp(m_loc - M_run) BEFORE the MFMA (B col = row).
//   One s_barrier per tile (P/ml double-buffered); K dbuf global_load_lds
//   with counted vmcnt(4); acc 64 + Q 32 + V 32 -> ~160 VGPR, (256,3)
//   => 3 blocks/CU (12 waves/CU). Scale 0.25 folded into tT.
//
// ws layout (bytes): same as R4.

#define NTOK 9409
#define NP   9472
#define C1V  256
#define C2V  512
#define KD   1024
#define BN_INV 0.9999950000374997f

typedef _Float16 f16;
typedef _Float16 f16x8 __attribute__((ext_vector_type(8)));
typedef _Float16 f16x4 __attribute__((ext_vector_type(4)));
typedef _Float16 f16x2 __attribute__((ext_vector_type(2)));
typedef float    f32x4 __attribute__((ext_vector_type(4)));

typedef const __attribute__((address_space(1))) unsigned int* gp_t;
typedef __attribute__((address_space(3))) unsigned int* lp_t;
#define GLOAD_LDS16(gsrc, ldst) \
  __builtin_amdgcn_global_load_lds((gp_t)(const void*)(gsrc), (lp_t)(void*)(ldst), 16, 0, 0)

// ---------------------------------------------------------------------------
// cvt_w: wt16[o][k] = wt*gam*inv (BN fold), wg16, wo16 plain; btf = bt*gam*inv+bet
// ---------------------------------------------------------------------------
__global__ __launch_bounds__(256) void cvt_w_kernel(
    const float* __restrict__ wt, const float* __restrict__ bt,
    const float* __restrict__ gam, const float* __restrict__ bet,
    const float* __restrict__ wg, const float* __restrict__ wo,
    f16* __restrict__ wt16, f16* __restrict__ wg16, f16* __restrict__ wo16,
    float* __restrict__ btf) {
  if (blockIdx.x == 1024) {
    int o = threadIdx.x;
    btf[o] = bt[o] * (gam[o] * BN_INV) + bet[o];
    return;
  }
  int i4 = (blockIdx.x * 256 + threadIdx.x) * 4;
  if (i4 < 262144) {
    float4 v = *(const float4*)(wt + i4);
    float s = gam[i4 >> 10] * BN_INV;
    f16x4 o; o[0]=(f16)(v.x*s); o[1]=(f16)(v.y*s); o[2]=(f16)(v.z*s); o[3]=(f16)(v.w*s);
    *(f16x4*)(wt16 + i4) = o;
  } else if (i4 < 262144 + 524288) {
    int j = i4 - 262144;
    float4 v = *(const float4*)(wg + j);
    f16x4 o; o[0]=(f16)v.x; o[1]=(f16)v.y; o[2]=(f16)v.z; o[3]=(f16)v.w;
    *(f16x4*)(wg16 + j) = o;
  } else {
    int j = i4 - 786432;
    float4 v = *(const float4*)(wo + j);
    f16x4 o; o[0]=(f16)v.x; o[1]=(f16)v.y; o[2]=(f16)v.z; o[3]=(f16)v.w;
    *(f16x4*)(wo16 + j) = o;
  }
}

// ---------------------------------------------------------------------------
// xpose: xT[n][k] f16; rows n>=9409 zeroed.
// ---------------------------------------------------------------------------
__global__ __launch_bounds__(256) void xpose_kernel(
    const float* __restrict__ x, const float* __restrict__ pos,
    f16* __restrict__ xT) {
  __shared__ f16 tile[64 * 68];
  const int k0 = blockIdx.x * 64;
  const int n0 = blockIdx.y * 64;
  const int tid = threadIdx.x;
  {
    const int kl = tid >> 4;
    const int nl = (tid & 15) * 4;
#pragma unroll
    for (int i = 0; i < 4; ++i) {
      int k = k0 + i * 16 + kl;
      const float* src = (k < 512) ? (x + (size_t)k * NTOK) : (pos + (size_t)(k - 512) * NTOK);
#pragma unroll
      for (int dd = 0; dd < 4; ++dd) {
        int n = n0 + nl + dd;
        float v = (n < NTOK) ? src[n] : 0.f;
        tile[(nl + dd) * 68 + i * 16 + kl] = (f16)v;
      }
    }
  }
  __syncthreads();
  {
    const int nl = tid >> 2;
    const int kc = (tid & 3) * 16;
    const int n = n0 + nl;
    f16x4 a = *(const f16x4*)(tile + nl * 68 + kc);
    f16x4 b = *(const f16x4*)(tile + nl * 68 + kc + 4);
    f16x4 c = *(const f16x4*)(tile + nl * 68 + kc + 8);
    f16x4 d = *(const f16x4*)(tile + nl * 68 + kc + 12);
    f16x8 v0, v1;
#pragma unroll
    for (int jj = 0; jj < 4; ++jj) { v0[jj] = a[jj]; v0[4 + jj] = b[jj]; v1[jj] = c[jj]; v1[4 + jj] = d[jj]; }
    if (n >= NTOK) {
#pragma unroll
      for (int jj = 0; jj < 8; ++jj) { v0[jj] = (f16)0.f; v1[jj] = (f16)0.f; }
    }
    f16* dst = xT + (size_t)n * KD + k0 + kc;
    *(f16x8*)(dst) = v0;
    *(f16x8*)(dst + 8) = v1;
  }
}

// ---------------------------------------------------------------------------
// proj_theta: tT[n][o] = 0.25*relu(sum_k xT[n][k]*wt16[o][k] + btf[o]);
// pad rows written as 0. (0.25 = 1/sqrt(16) folded; theta==phi shared)
// ---------------------------------------------------------------------------
__global__ __launch_bounds__(256) void proj_theta_kernel(
    const f16* __restrict__ xT, const f16* __restrict__ wt16,
    const float* __restrict__ btf, f16* __restrict__ tT) {
  const int n0 = blockIdx.x * 128;
  const int o0 = blockIdx.y * 64;
  const int tid = threadIdx.x;
  const int w = tid >> 6, lane = tid & 63, l15 = lane & 15, l4 = lane >> 4;
  const int nb = n0 + w * 32;
  f32x4 acc[2][4];
#pragma unroll
  for (int i = 0; i < 2; ++i)
#pragma unroll
    for (int j = 0; j < 4; ++j) acc[i][j] = (f32x4){0.f,0.f,0.f,0.f};
  const f16* ap0 = xT + (size_t)(nb + l15) * KD + l4 * 8;
  const f16* bp  = wt16 + (size_t)(o0 + l15) * KD + l4 * 8;
#pragma unroll 2
  for (int k0 = 0; k0 < KD; k0 += 32) {
    f16x8 a0 = *(const f16x8*)(ap0 + k0);
    f16x8 a1 = *(const f16x8*)(ap0 + 16 * KD + k0);
    f16x8 b[4];
#pragma unroll
    for (int fo = 0; fo < 4; ++fo) b[fo] = *(const f16x8*)(bp + fo * 16 * KD + k0);
#pragma unroll
    for (int fo = 0; fo < 4; ++fo) {
      acc[0][fo] = __builtin_amdgcn_mfma_f32_16x16x32_f16(a0, b[fo], acc[0][fo], 0, 0, 0);
      acc[1][fo] = __builtin_amdgcn_mfma_f32_16x16x32_f16(a1, b[fo], acc[1][fo], 0, 0, 0);
    }
  }
#pragma unroll
  for (int fm = 0; fm < 2; ++fm)
#pragma unroll
    for (int fo = 0; fo < 4; ++fo) {
      int o = o0 + fo * 16 + l15;
      float bb = btf[o];
#pragma unroll
      for (int j = 0; j < 4; ++j) {
        int n = nb + fm * 16 + l4 * 4 + j;
        float v = (n < NTOK) ? 0.25f * fmaxf(acc[fm][fo][j] + bb, 0.f) : 0.f;
        tT[(size_t)n * C1V + o] = (f16)v;
      }
    }
}

// ---------------------------------------------------------------------------
// proj_g: gc[c][n] = sum_k wg16[c][k]*xT[n][k] + bg[c]
// ---------------------------------------------------------------------------
__global__ __launch_bounds__(256) void proj_g_kernel(
    const f16* __restrict__ xT, const f16* __restrict__ wg16,
    const float* __restrict__ bg, f16* __restrict__ gc) {
  const int n0 = blockIdx.x * 128;
  const int c0 = blockIdx.y * 128;
  const int tid = threadIdx.x;
  const int w = tid >> 6, lane = tid & 63, l15 = lane & 15, l4 = lane >> 4;
  const int cb = c0 + (w >> 1) * 64, nb = n0 + (w & 1) * 64;
  f32x4 acc[4][4];
#pragma unroll
  for (int i = 0; i < 4; ++i)
#pragma unroll
    for (int j = 0; j < 4; ++j) acc[i][j] = (f32x4){0.f,0.f,0.f,0.f};
  const f16* ap = wg16 + (size_t)(cb + l15) * KD + l4 * 8;
  const f16* bp = xT + (size_t)(nb + l15) * KD + l4 * 8;
  for (int k0 = 0; k0 < KD; k0 += 32) {
    f16x8 a[4], b[4];
#pragma unroll
    for (int fc = 0; fc < 4; ++fc) a[fc] = *(const f16x8*)(ap + fc * 16 * KD + k0);
#pragma unroll
    for (int fn = 0; fn < 4; ++fn) b[fn] = *(const f16x8*)(bp + fn * 16 * KD + k0);
#pragma unroll
    for (int fc = 0; fc < 4; ++fc)
#pragma unroll
      for (int fn = 0; fn < 4; ++fn)
        acc[fc][fn] = __builtin_amdgcn_mfma_f32_16x16x32_f16(a[fc], b[fn], acc[fc][fn], 0, 0, 0);
  }
#pragma unroll
  for (int fc = 0; fc < 4; ++fc)
#pragma unroll
    for (int j = 0; j < 4; ++j) {
      int c = cb + fc * 16 + l4 * 4 + j;
      float bb = bg[c];
#pragma unroll
      for (int fn = 0; fn < 4; ++fn) {
        int n = nb + fn * 16 + l15;
        gc[(size_t)c * NP + n] = (f16)(acc[fc][fn][j] + bb);
      }
    }
}

// ---------------------------------------------------------------------------
// attn: flash partials. 1180 blocks = 295 row-blocks(32 q-rows) x 4 m-quarters.
// 4 waves: QK wave (qr=w&1, qm=w>>1) = rows 16qr x keys 16qm (swapped MFMA).
// PV: wave w = c-slice [128w,128w+128), V direct from L2, B-frag = P rescaled
// in-reg by exp(m_loc - M_run). One barrier/tile; P/ml double-buffered.
// ---------------------------------------------------------------------------
__global__ __launch_bounds__(256, 3) void attn_kernel(
    const f16* __restrict__ tT, const f16* __restrict__ gc,
    f16* __restrict__ part, float* __restrict__ stats) {
  __shared__ char lds[32768 + 5120 + 1024];  // K dbuf 2x16KB | P dbuf 2x[32][40]f16 | ml dbuf 2x[2][32]f32x2
  const int bid = blockIdx.x;
  const int q = bid & 3;
  const int tid = threadIdx.x;
  const int w = tid >> 6, lane = tid & 63, l15 = lane & 15, l4 = lane >> 4;
  const int qr = w & 1, qm = w >> 1;
  const int cs = w * 128;

  // Q fragments (B-layout: col=l15 -> q-row, k = kk*32 + l4*8)
  f16x8 Qf[8];
  {
    const f16* qp = tT + (size_t)((bid >> 2) * 32 + qr * 16 + l15) * C1V + l4 * 8;
#pragma unroll
    for (int kk = 0; kk < 8; ++kk) Qf[kk] = *(const f16x8*)(qp + kk * 32);
  }
  // K ds_read swizzled offset decomposition
  const int mloc = qm * 16 + l15;
  const int kkx = (mloc >> 2) & 1;
  const int kbase = mloc * 512 + ((l4 ^ (mloc & 3)) << 4);
  // staging source offsets (inverse-swizzled global, linear LDS dest)
  int soff[4];
#pragma unroll
  for (int i = 0; i < 4; ++i) {
    int m_ = i * 8 + (tid >> 5), s_ = tid & 31;
    soff[i] = m_ * C1V + ((s_ ^ (m_ & 7)) << 3);
  }
  const int sdst = tid * 16;
  const f16* vp = gc + (size_t)(cs + l15) * NP + l4 * 8;  // V A-frag lane base

  f32x4 acc[8][2];
#pragma unroll
  for (int cf = 0; cf < 8; ++cf)
#pragma unroll
    for (int rf = 0; rf < 2; ++rf) acc[cf][rf] = (f32x4){0.f,0.f,0.f,0.f};
  float Mr[2] = {-1e30f, -1e30f}, Lr[2] = {0.f, 0.f};

#define KPREF(tt, dstbase)                                        \
  {                                                               \
    const f16* kb_ = tT + (size_t)(tt) * 32 * C1V;                \
    _Pragma("unroll")                                             \
    for (int i_ = 0; i_ < 4; ++i_)                                \
      GLOAD_LDS16(kb_ + soff[i_], (dstbase) + i_ * 4096 + sdst);  \
  }

  const int tt0 = q * 74;
  KPREF(tt0, lds)
  asm volatile("s_waitcnt vmcnt(0)" ::: "memory");
  __builtin_amdgcn_s_barrier();

  for (int ti = 0; ti < 74; ++ti) {
    const int tt = tt0 + ti;
    const int m0 = tt * 32;
    const int cur = ti & 1;
    char* Pb = lds + 32768 + cur * 2560;       // f16 [32 r][40]
    char* mlb = lds + 32768 + 5120 + cur * 512; // f32x2 [2 h][32 r]
    // ---- stage K(t+1) first (oldest in vmcnt), then V first half ----
    if (ti + 1 < 74) KPREF(tt + 1, lds + (cur ^ 1) * 16384)
    __builtin_amdgcn_sched_barrier(0);  // pin order: KPREF before vfA
    f16x8 vfA[4];
#pragma unroll
    for (int cf = 0; cf < 4; ++cf)
      vfA[cf] = *(const f16x8*)(vp + (size_t)cf * 16 * NP + m0);
    // ---- QK (swapped): S^T quadrant; D col=l15=row r, D row = m idx ----
    const char* kbuf = lds + cur * 16384;
    f32x4 s0 = {0.f,0.f,0.f,0.f};
    __builtin_amdgcn_s_setprio(1);
#pragma unroll
    for (int kk = 0; kk < 8; ++kk) {
      f16x8 kf = *(const f16x8*)(kbuf + kbase + ((kk ^ kkx) << 6));
      s0 = __builtin_amdgcn_mfma_f32_16x16x32_f16(kf, Qf[kk], s0, 0, 0, 0);
    }
    __builtin_amdgcn_s_setprio(0);
    // ---- local softmax: row r=l15 fixed per lane; m = qm*16 + l4*4 + j ----
    float sv[4];
#pragma unroll
    for (int j = 0; j < 4; ++j) sv[j] = s0[j];
    if (m0 + 32 > NTOK) {
#pragma unroll
      for (int j = 0; j < 4; ++j)
        if (m0 + qm * 16 + l4 * 4 + j >= NTOK) sv[j] = -1e30f;
    }
    float mx = fmaxf(fmaxf(sv[0], sv[1]), fmaxf(sv[2], sv[3]));
    mx = fmaxf(mx, __shfl_xor(mx, 16));
    mx = fmaxf(mx, __shfl_xor(mx, 32));
    float p[4], ls = 0.f;
#pragma unroll
    for (int j = 0; j < 4; ++j) { p[j] = __expf(sv[j] - mx); ls += p[j]; }
    ls += __shfl_xor(ls, 16);
    ls += __shfl_xor(ls, 32);
    {
      f16x4 pw;
#pragma unroll
      for (int j = 0; j < 4; ++j) pw[j] = (f16)p[j];
      *(f16x4*)(Pb + (qr * 16 + l15) * 80 + qm * 32 + l4 * 8) = pw;
      if (l4 == 0) *(float2*)(mlb + (qm * 32 + qr * 16 + l15) * 8) = make_float2(mx, ls);
    }
    // ---- retire K(t+1) stage (vfA are the 4 newest), publish P/ml ----
    asm volatile("s_waitcnt vmcnt(4)" ::: "memory");
    asm volatile("s_waitcnt lgkmcnt(0)" ::: "memory");
    __builtin_amdgcn_s_barrier();
    __builtin_amdgcn_sched_barrier(0);
    // ---- V second half ----
    f16x8 vfB[4];
#pragma unroll
    for (int cf = 0; cf < 4; ++cf)
      vfB[cf] = *(const f16x8*)(vp + (size_t)(cf + 4) * 16 * NP + m0);
    // ---- softmax correction (per rf; h = l4>>1) ----
    float mlx[2], mll[2], mox[2], mol[2], Mn[2];
    int grow = 0;
#pragma unroll
    for (int rf = 0; rf < 2; ++rf) {
      float2 mlv = *(const float2*)(mlb + ((l4 >> 1) * 32 + rf * 16 + l15) * 8);
      mlx[rf] = mlv.x; mll[rf] = mlv.y;
      mox[rf] = __shfl_xor(mlv.x, 32);
      mol[rf] = __shfl_xor(mlv.y, 32);
      float mx2 = fmaxf(mlx[rf], mox[rf]);
      Mn[rf] = (mx2 > Mr[rf] + 8.f) ? mx2 : Mr[rf];   // T13 defer-max
      grow |= (Mn[rf] != Mr[rf]) ? 1 : 0;
    }
    if (__any(grow)) {
#pragma unroll
      for (int rf = 0; rf < 2; ++rf) {
        float a = __expf(Mr[rf] - Mn[rf]);
        Mr[rf] = Mn[rf];
        Lr[rf] *= a;
#pragma unroll
        for (int cf = 0; cf < 8; ++cf)
#pragma unroll
          for (int j = 0; j < 4; ++j) acc[cf][rf][j] *= a;
      }
    }
    f16x8 Pf[2];
#pragma unroll
    for (int rf = 0; rf < 2; ++rf) {
      float ah = __expf(mlx[rf] - Mr[rf]);
      float ao = __expf(mox[rf] - Mr[rf]);
      Lr[rf] += ah * mll[rf] + ao * mol[rf];
      Pf[rf] = *(const f16x8*)(Pb + (rf * 16 + l15) * 80 + l4 * 16);
      f16 ah16 = (f16)ah;
#pragma unroll
      for (int e = 0; e < 8; ++e) Pf[rf][e] *= ah16;
    }
    // ---- PV (swapped): acc[cf][rf] += V[c][m] x P[r][m] ----
    __builtin_amdgcn_s_setprio(1);
#pragma unroll
    for (int cf = 0; cf < 4; ++cf)
#pragma unroll
      for (int rf = 0; rf < 2; ++rf)
        acc[cf][rf] = __builtin_amdgcn_mfma_f32_16x16x32_f16(vfA[cf], Pf[rf], acc[cf][rf], 0, 0, 0);
#pragma unroll
    for (int cf = 0; cf < 4; ++cf)
#pragma unroll
      for (int rf = 0; rf < 2; ++rf)
        acc[cf + 4][rf] = __builtin_amdgcn_mfma_f32_16x16x32_f16(vfB[cf], Pf[rf], acc[cf + 4][rf], 0, 0, 0);
    __builtin_amdgcn_s_setprio(0);
  }
#undef KPREF
  // ---- epilogue: every wave has full M/L (rows 0..31) ----
  float rinv[2];
#pragma unroll
  for (int rf = 0; rf < 2; ++rf) rinv[rf] = 1.0f / Lr[rf];
  const int prow = bid * 32;
  if (w == 0 && l4 == 0) {
#pragma unroll
    for (int rf = 0; rf < 2; ++rf) {
      stats[(prow + rf * 16 + l15) * 2] = Mr[rf];
      stats[(prow + rf * 16 + l15) * 2 + 1] = Lr[rf];
    }
  }
#pragma unroll
  for (int cf = 0; cf < 8; ++cf)
#pragma unroll
    for (int rf = 0; rf < 2; ++rf) {
      f16x4 st;
#pragma unroll
      for (int j = 0; j < 4; ++j) st[j] = (f16)(acc[cf][rf][j] * rinv[rf]);
      *(f16x4*)(part + (size_t)(prow + rf * 16 + l15) * C2V + cs + cf * 16 + l4 * 4) = st;
    }
}

// ---------------------------------------------------------------------------
// merge: combine 4 m-split partials per row (32-row blocks) -> yT[n][512] f16
// ---------------------------------------------------------------------------
__global__ __launch_bounds__(256) void merge_kernel(
    const f16* __restrict__ part, const float* __restrict__ stats,
    f16* __restrict__ yT) {
  const int n = blockIdx.x;
  const int rb = n >> 5, rl = n & 31;
  float Mq[4], Lq[4];
#pragma unroll
  for (int qq = 0; qq < 4; ++qq) {
    int pr = (rb * 4 + qq) * 32 + rl;
    Mq[qq] = stats[pr * 2];
    Lq[qq] = stats[pr * 2 + 1];
  }
  float Ms = fmaxf(fmaxf(Mq[0], Mq[1]), fmaxf(Mq[2], Mq[3]));
  float wq[4], lt = 0.f;
#pragma unroll
  for (int qq = 0; qq < 4; ++qq) { wq[qq] = __expf(Mq[qq] - Ms) * Lq[qq]; lt += wq[qq]; }
  float inv = 1.f / lt;
  const int c = threadIdx.x * 2;
  float y0 = 0.f, y1 = 0.f;
#pragma unroll
  for (int qq = 0; qq < 4; ++qq) {
    f16x2 v = *(const f16x2*)(part + (size_t)((rb * 4 + qq) * 32 + rl) * C2V + c);
    y0 += wq[qq] * (float)v[0];
    y1 += wq[qq] * (float)v[1];
  }
  f16x2 o; o[0] = (f16)(y0 * inv); o[1] = (f16)(y1 * inv);
  *(f16x2*)(yT + (size_t)n * C2V + c) = o;
}

// ---------------------------------------------------------------------------
// out_gemm: out[o][n] f32 = sum_c wo16[o][c]*yT[n][c] + bo[o]
// ---------------------------------------------------------------------------
__global__ __launch_bounds__(256) void out_gemm_kernel(
    const f16* __restrict__ yT, const f16* __restrict__ wo16,
    const float* __restrict__ bo, float* __restrict__ out) {
  const int n0 = blockIdx.x * 128;
  const int o0 = blockIdx.y * 128;
  const int tid = threadIdx.x;
  const int w = tid >> 6, lane = tid & 63, l15 = lane & 15, l4 = lane >> 4;
  const int ob = o0 + (w >> 1) * 64, nb = n0 + (w & 1) * 64;
  f32x4 acc[4][4];
#pragma unroll
  for (int i = 0; i < 4; ++i)
#pragma unroll
    for (int j = 0; j < 4; ++j) acc[i][j] = (f32x4){0.f,0.f,0.f,0.f};
  const f16* ap = wo16 + (size_t)(ob + l15) * C2V + l4 * 8;
  const f16* bp = yT + (size_t)(nb + l15) * C2V + l4 * 8;
  for (int k0 = 0; k0 < C2V; k0 += 32) {
    f16x8 a[4], b[4];
#pragma unroll
    for (int fc = 0; fc < 4; ++fc) a[fc] = *(const f16x8*)(ap + fc * 16 * C2V + k0);
#pragma unroll
    for (int fn = 0; fn < 4; ++fn) b[fn] = *(const f16x8*)(bp + fn * 16 * C2V + k0);
#pragma unroll
    for (int fc = 0; fc < 4; ++fc)
#pragma unroll
      for (int fn = 0; fn < 4; ++fn)
        acc[fc][fn] = __builtin_amdgcn_mfma_f32_16x16x32_f16(a[fc], b[fn], acc[fc][fn], 0, 0, 0);
  }
#pragma unroll
  for (int fn = 0; fn < 4; ++fn) {
    int n = nb + fn * 16 + l15;
    if (n >= NTOK) continue;
#pragma unroll
    for (int fc = 0; fc < 4; ++fc)
#pragma unroll
      for (int j = 0; j < 4; ++j) {
        int o = ob + fc * 16 + l4 * 4 + j;
        out[(size_t)o * NTOK + n] = acc[fc][fn][j] + bo[o];
      }
  }
}

// ---------------------------------------------------------------------------
extern "C" void kernel_launch(void* const* d_in, const int* in_sizes, int n_in,
                              void* d_out, int out_size, void* d_ws, size_t ws_size,
                              hipStream_t stream) {
  const float* x   = (const float*)d_in[0];
  const float* pos = (const float*)d_in[1];
  const float* wt  = (const float*)d_in[2];
  const float* bt  = (const float*)d_in[3];
  const float* gam = (const float*)d_in[4];
  const float* bet = (const float*)d_in[5];
  const float* wg  = (const float*)d_in[6];
  const float* bg  = (const float*)d_in[7];
  const float* wo  = (const float*)d_in[8];
  const float* bo  = (const float*)d_in[9];
  float* out = (float*)d_out;

  char* ws = (char*)d_ws;
  f16*   tT    = (f16*)(ws + 0);
  f16*   gc    = (f16*)(ws + 4849664);
  f16*   wt16  = (f16*)(ws + 14548992);
  f16*   wg16  = (f16*)(ws + 15073280);
  f16*   wo16  = (f16*)(ws + 16121856);
  float* btf   = (float*)(ws + 16646144);
  float* stats = (float*)(ws + 16647168);
  f16*   yT    = (f16*)(ws + 16950272);
  f16*   part  = (f16*)(ws + 26649600);
  f16*   xT    = (f16*)(ws + 26649600);  // union with part (xT dead before attn)

  cvt_w_kernel<<<1025, 256, 0, stream>>>(wt, bt, gam, bet, wg, wo, wt16, wg16, wo16, btf);
  xpose_kernel<<<dim3(16, 148), 256, 0, stream>>>(x, pos, xT);
  proj_theta_kernel<<<dim3(74, 4), 256, 0, stream>>>(xT, wt16, btf, tT);
  proj_g_kernel<<<dim3(74, 4), 256, 0, stream>>>(xT, wg16, bg, gc);
  attn_kernel<<<1180, 256, 0, stream>>>(tT, gc, part, stats);
  merge_kernel<<<NTOK, 256, 0, stream>>>(part, stats, yT);
  out_gemm_kernel<<<dim3(74, 4), 256, 0, stream>>>(yT, wo16, bo, out);
}